// Round 8
// baseline (265.380 us; speedup 1.0000x reference)
//
#include <hip/hip_runtime.h>
#include <math.h>

using bf16x8 = __attribute__((ext_vector_type(8))) short;
using f32x4  = __attribute__((ext_vector_type(4))) float;
using f32x16 = __attribute__((ext_vector_type(16))) float;

namespace {
constexpr int kB  = 4;
constexpr int kLQ = 1024;
constexpr int kLK = 2048;
constexpr int kH  = 1024;
constexpr int kHD = 64;
}

__device__ __forceinline__ unsigned short f2bf(float x) {
  union { float f; unsigned int u; } v; v.f = x;
  unsigned int r = v.u + 0x7fffu + ((v.u >> 16) & 1u);   // RNE
  return (unsigned short)(r >> 16);
}
__device__ __forceinline__ unsigned int bfT(float x) {   // truncation, as u32
  union { float f; unsigned int u; } v; v.f = x;
  return v.u >> 16;
}

// async global->LDS 16B copy
typedef const __attribute__((address_space(1))) unsigned int guint_t;
typedef __attribute__((address_space(3))) unsigned int luint_t;
__device__ __forceinline__ void g2l16(const void* g, void* l) {
  __builtin_amdgcn_global_load_lds(
      (guint_t*)g,
      (luint_t*)(unsigned int)(unsigned long long)l,
      16, 0, 0);
}

// --------- fused prep: fp32->bf16 casts (q,k,v) + 4 weight transposes --------
__global__ __launch_bounds__(256) void prep_kernel(
    const float* __restrict__ q, const float* __restrict__ k,
    const float* __restrict__ v, const float* __restrict__ Wq,
    const float* __restrict__ Wk, const float* __restrict__ Wv,
    const float* __restrict__ Wo, unsigned short* __restrict__ qo,
    unsigned short* __restrict__ ko, unsigned short* __restrict__ vo,
    unsigned short* __restrict__ WqT, unsigned short* __restrict__ WkT,
    unsigned short* __restrict__ WvT, unsigned short* __restrict__ WoT)
{
  __shared__ float tile[64][65];
  const int t = threadIdx.x;
  if (blockIdx.x < 5632) {
    int c = blockIdx.x * 256 + t;
    const float* src; unsigned short* dst;
    if (c < 393216)      { src = q; dst = qo; }
    else if (c < 917504) { src = k; dst = ko; c -= 393216; }
    else                 { src = v; dst = vo; c -= 917504; }
    const int i = c * 8;
    const float4 a = *(const float4*)(src + i);
    const float4 b = *(const float4*)(src + i + 4);
    uint4 o;
    o.x = (unsigned int)f2bf(a.x) | ((unsigned int)f2bf(a.y) << 16);
    o.y = (unsigned int)f2bf(a.z) | ((unsigned int)f2bf(a.w) << 16);
    o.z = (unsigned int)f2bf(b.x) | ((unsigned int)f2bf(b.y) << 16);
    o.w = (unsigned int)f2bf(b.z) | ((unsigned int)f2bf(b.w) << 16);
    *(uint4*)(dst + i) = o;
    return;
  }
  int id = blockIdx.x - 5632;
  const float* W; unsigned short* Wt; int Kd;
  if (id < 192)      { W = Wq; Wt = WqT; Kd = 768; }
  else if (id < 320) { W = Wk; Wt = WkT; Kd = 512;  id -= 192; }
  else if (id < 448) { W = Wv; Wt = WvT; Kd = 512;  id -= 320; }
  else               { W = Wo; Wt = WoT; Kd = 1024; id -= 448; }
  const int Nd = 1024;
  const int n0 = (id & 15) * 64;
  const int k0 = (id >> 4) * 64;
  const int rr = t >> 4;
  const int c4 = t & 15;
#pragma unroll
  for (int i = 0; i < 4; ++i) {
    const int row = i * 16 + rr;
    const float4 vv = *(const float4*)(W + (size_t)(k0 + row) * Nd + n0 + c4 * 4);
    tile[row][c4*4+0] = vv.x; tile[row][c4*4+1] = vv.y;
    tile[row][c4*4+2] = vv.z; tile[row][c4*4+3] = vv.w;
  }
  __syncthreads();
#pragma unroll
  for (int i = 0; i < 4; ++i) {
    const int n = i * 16 + rr;
    ushort4 o;
    o.x = f2bf(tile[c4*4+0][n]); o.y = f2bf(tile[c4*4+1][n]);
    o.z = f2bf(tile[c4*4+2][n]); o.w = f2bf(tile[c4*4+3][n]);
    *(ushort4*)(Wt + (size_t)(n0 + n) * Kd + k0 + c4 * 4) = o;
  }
}

// ---- 128x256 GEMM body (qkv): BK=32, double-buffered g2l, 4 waves -----------
__device__ __forceinline__ void gemm_body256(
    const unsigned short* __restrict__ A, const unsigned short* __restrict__ Bt,
    const float* __restrict__ bias, unsigned short* __restrict__ Cout,
    int N, int K, int bx, int by, int mode, char* lds)
{
  const int t    = threadIdx.x;
  const int lane = t & 63;
  const int w    = t >> 6;
  const int l15  = lane & 15;
  const int lq8  = (lane >> 4) * 8;
  const int lq4  = (lane >> 4) * 4;
  const int r0   = by * 128;
  const int c0   = bx * 256;
  const int wm   = w >> 1, wn = w & 1;

  f32x4 acc[4][8] = {};

#pragma unroll
  for (int i = 0; i < 6; ++i) {
    const int g = w * 6 + i;
    const unsigned short* src = (g < 8) ? A : Bt;
    const int rbase = (g < 8) ? (r0 + g * 16) : (c0 + (g - 8) * 16);
    g2l16(src + (size_t)(rbase + l15) * K + lq8, lds + g * 1024 + lane * 16);
  }

  int pb = 0;
  for (int k0 = 0; k0 < K; k0 += 32, pb ^= 1) {
    __syncthreads();
    char* buf = lds + pb * 24576;
    if (k0 + 32 < K) {
      char* nbuf = lds + (pb ^ 1) * 24576;
#pragma unroll
      for (int i = 0; i < 6; ++i) {
        const int g = w * 6 + i;
        const unsigned short* src = (g < 8) ? A : Bt;
        const int rbase = (g < 8) ? (r0 + g * 16) : (c0 + (g - 8) * 16);
        g2l16(src + (size_t)(rbase + l15) * K + k0 + 32 + lq8, nbuf + g * 1024 + lane * 16);
      }
    }
    bf16x8 af[4], bfr[8];
#pragma unroll
    for (int i = 0; i < 4; ++i) af[i]  = *(const bf16x8*)(buf + (wm*4 + i) * 1024 + lane * 16);
#pragma unroll
    for (int j = 0; j < 8; ++j) bfr[j] = *(const bf16x8*)(buf + 8192 + (wn*8 + j) * 1024 + lane * 16);
#pragma unroll
    for (int i = 0; i < 4; ++i)
#pragma unroll
      for (int j = 0; j < 8; ++j)
        acc[i][j] = __builtin_amdgcn_mfma_f32_16x16x32_bf16(af[i], bfr[j], acc[i][j], 0, 0, 0);
  }

#pragma unroll
  for (int j = 0; j < 8; ++j) {
    const int col = c0 + wn * 128 + j * 16 + l15;
    const float bcol = bias[col];
#pragma unroll
    for (int i = 0; i < 4; ++i) {
      const int row = r0 + wm * 64 + i * 16 + lq4;
      if (mode == 1) {
#pragma unroll
        for (int r = 0; r < 4; ++r) Cout[(size_t)(row + r) * N + col] = f2bf(acc[i][j][r] + bcol);
      } else {
        const int bb = row >> 11;            // kLK = 2048
        const int lk = row & 2047;
        ushort4 o;
        o.x = f2bf(acc[i][j][0] + bcol); o.y = f2bf(acc[i][j][1] + bcol);
        o.z = f2bf(acc[i][j][2] + bcol); o.w = f2bf(acc[i][j][3] + bcol);
        *(ushort4*)(Cout + (size_t)(bb * kH + col) * kLK + lk) = o;
      }
    }
  }
}

// fused Q/K/V projections: blocks 0..127 Q | 128..383 K | 384..639 V
__global__ __launch_bounds__(256) void qkv_gemm_kernel(
    const unsigned short* __restrict__ qA, const unsigned short* __restrict__ WqT,
    const float* __restrict__ bq, unsigned short* __restrict__ Qb,
    const unsigned short* __restrict__ kA, const unsigned short* __restrict__ WkT,
    const float* __restrict__ bk, unsigned short* __restrict__ Kb,
    const unsigned short* __restrict__ vA, const unsigned short* __restrict__ WvT,
    const float* __restrict__ bv, unsigned short* __restrict__ Vtw)
{
  __shared__ __align__(16) char lds[49152];
  int id = blockIdx.x;
  if (id < 128) {
    gemm_body256(qA, WqT, bq, Qb, 1024, 768, id & 3, id >> 2, 1, lds);
  } else if (id < 384) {
    id -= 128;
    gemm_body256(kA, WkT, bk, Kb, 1024, 512, id & 3, id >> 2, 1, lds);
  } else {
    id -= 384;
    gemm_body256(vA, WvT, bv, Vtw, 1024, 512, id & 3, id >> 2, 2, lds);
  }
}

// out projection: 128x128 tile, BK=32, double-buffered, fp32 out, grid (8,32)
__global__ __launch_bounds__(256) void out_gemm_kernel(
    const unsigned short* __restrict__ A, const unsigned short* __restrict__ Bt,
    const float* __restrict__ bias, float* __restrict__ C)
{
  __shared__ __align__(16) char lds[32768];
  const int t    = threadIdx.x;
  const int lane = t & 63;
  const int w    = t >> 6;
  const int l15  = lane & 15;
  const int lq8  = (lane >> 4) * 8;
  const int lq4  = (lane >> 4) * 4;
  const int r0   = blockIdx.y * 128;
  const int c0   = blockIdx.x * 128;
  const int wm   = w >> 1, wn = w & 1;
  const int N = 1024, K = 1024;

  f32x4 acc[4][4] = {};

#pragma unroll
  for (int i = 0; i < 4; ++i) {
    const int g = w * 4 + i;
    const unsigned short* src = (g < 8) ? A : Bt;
    const int rbase = (g < 8) ? (r0 + g * 16) : (c0 + (g - 8) * 16);
    g2l16(src + (size_t)(rbase + l15) * K + lq8, lds + g * 1024 + lane * 16);
  }
  int pb = 0;
  for (int k0 = 0; k0 < K; k0 += 32, pb ^= 1) {
    __syncthreads();
    char* buf = lds + pb * 16384;
    if (k0 + 32 < K) {
      char* nbuf = lds + (pb ^ 1) * 16384;
#pragma unroll
      for (int i = 0; i < 4; ++i) {
        const int g = w * 4 + i;
        const unsigned short* src = (g < 8) ? A : Bt;
        const int rbase = (g < 8) ? (r0 + g * 16) : (c0 + (g - 8) * 16);
        g2l16(src + (size_t)(rbase + l15) * K + k0 + 32 + lq8, nbuf + g * 1024 + lane * 16);
      }
    }
    bf16x8 af[4], bfr[4];
#pragma unroll
    for (int i = 0; i < 4; ++i) af[i]  = *(const bf16x8*)(buf + (wm*4 + i) * 1024 + lane * 16);
#pragma unroll
    for (int j = 0; j < 4; ++j) bfr[j] = *(const bf16x8*)(buf + 8192 + (wn*4 + j) * 1024 + lane * 16);
#pragma unroll
    for (int i = 0; i < 4; ++i)
#pragma unroll
      for (int j = 0; j < 4; ++j)
        acc[i][j] = __builtin_amdgcn_mfma_f32_16x16x32_bf16(af[i], bfr[j], acc[i][j], 0, 0, 0);
  }
#pragma unroll
  for (int j = 0; j < 4; ++j) {
    const int col = c0 + wn * 64 + j * 16 + l15;
    const float bcol = bias[col];
#pragma unroll
    for (int i = 0; i < 4; ++i) {
      const int row = r0 + wm * 64 + i * 16 + lq4;
#pragma unroll
      for (int r = 0; r < 4; ++r) C[(size_t)(row + r) * N + col] = acc[i][j][r] + bcol;
    }
  }
}

// --------------- MFMA flash attention, 32x32 path, split-K=2 -----------------
// Q [B*LQ,H], K [B*LK,H], Vt [B*H,LK] bf16. Each block: 256 q-rows (4 waves x
// 64 q), half the kc-range (1024, 16 iters of 64). Computes S^T = K*Q^T with
// mfma_32x32x16 (C-layout rows = kc -> packed b64 P-stores), then O = P*V.
// Writes unnormalized fp32 O-partials + lsums; attn_reduce combines.
// Grid 512 = 2 blocks/CU; flat = (qb*2+s)*64 + bh keeps (b,h) on one XCD.
__global__ __launch_bounds__(256) void attn_mfma_kernel(
    const unsigned short* __restrict__ Q, const unsigned short* __restrict__ K,
    const unsigned short* __restrict__ Vt, float* __restrict__ Op0,
    float* __restrict__ Op1, float* __restrict__ Ls)
{
  // Kbuf dbuf 2x8K | Vbuf dbuf 2x8K @16384 | P @32768: 4 waves x 8KB
  __shared__ __align__(16) char lds[65536];
  const int t    = threadIdx.x;
  const int lane = t & 63;
  const int w    = t >> 6;
  const int l31  = lane & 31;
  const int h    = lane >> 5;
  const int flat = blockIdx.x;
  const int bh   = flat & 63;
  const int g8   = flat >> 6;
  const int s    = g8 & 1;
  const int qb   = g8 >> 1;
  const int hh   = bh & 15;
  const int b    = bh >> 4;
  const int q0   = qb * 256;
  const int kcb  = s * 1024;
  const int hoff = hh * kHD;
  const int qw   = q0 + w * 64;

  // Q B-frags: lane n=q=l31, k = h*8+j (d within 16-step)
  bf16x8 qf[2][4];
#pragma unroll
  for (int qt2 = 0; qt2 < 2; ++qt2)
#pragma unroll
    for (int ds_ = 0; ds_ < 4; ++ds_)
      qf[qt2][ds_] = *(const bf16x8*)(Q + (size_t)(b*kLQ + qw + qt2*32 + l31) * kH
                                        + hoff + ds_*16 + h*8);

  f32x16 oacc[2][2] = {};
  float lsum[2] = {0.f, 0.f};

  // prologue: prefetch tile 0 into buf 0 (16 chunks, 4 per wave)
#pragma unroll
  for (int i = 0; i < 4; ++i) {
    const int g = w * 4 + i;
    if (g < 8) {
      g2l16(K + (size_t)(b*kLK + kcb + (g >> 2)*32 + l31) * kH + hoff + (g & 3)*16 + h*8,
            lds + g * 1024 + lane * 16);
    } else {
      const int gg = g - 8;
      g2l16(Vt + (size_t)(b*kH + hoff + (gg >> 2)*32 + l31) * kLK + kcb + (gg & 3)*16 + h*8,
            lds + 16384 + gg * 1024 + lane * 16);
    }
  }

  char* const pbase = lds + 32768 + w * 8192;

  for (int kt = 0; kt < 16; ++kt) {
    __syncthreads();   // drains prefetch of tile kt (issued one full iter ago)
    char* kbuf = lds + (kt & 1) * 8192;
    char* vbuf = lds + 16384 + (kt & 1) * 8192;
    if (kt + 1 < 16) {
      char* nk = lds + ((kt + 1) & 1) * 8192;
      char* nv = lds + 16384 + ((kt + 1) & 1) * 8192;
      const int kc1 = kcb + (kt + 1) * 64;
#pragma unroll
      for (int i = 0; i < 4; ++i) {
        const int g = w * 4 + i;
        if (g < 8) {
          g2l16(K + (size_t)(b*kLK + kc1 + (g >> 2)*32 + l31) * kH + hoff + (g & 3)*16 + h*8,
                nk + g * 1024 + lane * 16);
        } else {
          const int gg = g - 8;
          g2l16(Vt + (size_t)(b*kH + hoff + (gg >> 2)*32 + l31) * kLK + kc1 + (gg & 3)*16 + h*8,
                nv + gg * 1024 + lane * 16);
        }
      }
    }

    // S^T = K * Q^T : 2 kc-tiles x 2 q-tiles, contraction d=64 in 4 steps
    f32x16 sacc[2][2] = {};
#pragma unroll
    for (int ds_ = 0; ds_ < 4; ++ds_) {
      const bf16x8 kf0 = *(const bf16x8*)(kbuf + (0*4 + ds_) * 1024 + lane * 16);
      const bf16x8 kf1 = *(const bf16x8*)(kbuf + (1*4 + ds_) * 1024 + lane * 16);
#pragma unroll
      for (int qt2 = 0; qt2 < 2; ++qt2) {
        sacc[0][qt2] = __builtin_amdgcn_mfma_f32_32x32x16_bf16(kf0, qf[qt2][ds_], sacc[0][qt2], 0, 0, 0);
        sacc[1][qt2] = __builtin_amdgcn_mfma_f32_32x32x16_bf16(kf1, qf[qt2][ds_], sacc[1][qt2], 0, 0, 0);
      }
    }

    // exp + packed b64 P-store into PV A-frag chunk order
#pragma unroll
    for (int kct2 = 0; kct2 < 2; ++kct2)
#pragma unroll
      for (int qt2 = 0; qt2 < 2; ++qt2)
#pragma unroll
        for (int g4 = 0; g4 < 4; ++g4) {
          const float e0 = __builtin_amdgcn_exp2f(sacc[kct2][qt2][g4*4+0] * 0.18033688011112042f);
          const float e1 = __builtin_amdgcn_exp2f(sacc[kct2][qt2][g4*4+1] * 0.18033688011112042f);
          const float e2 = __builtin_amdgcn_exp2f(sacc[kct2][qt2][g4*4+2] * 0.18033688011112042f);
          const float e3 = __builtin_amdgcn_exp2f(sacc[kct2][qt2][g4*4+3] * 0.18033688011112042f);
          lsum[qt2] += (e0 + e1) + (e2 + e3);
          uint2 u;
          u.x = bfT(e0) | (bfT(e1) << 16);
          u.y = bfT(e2) | (bfT(e3) << 16);
          *(uint2*)(pbase + (qt2*4 + kct2*2 + (g4 >> 1)) * 1024 +
                    (((g4 & 1) * 32) + l31) * 16 + 8*h) = u;
        }

    // O += P * V : contraction kc=64 in 4 steps (P wave-private; lgkmcnt auto)
#pragma unroll
    for (int ks = 0; ks < 4; ++ks) {
      const bf16x8 pf0 = *(const bf16x8*)(pbase + (0*4 + ks) * 1024 + lane * 16);
      const bf16x8 pf1 = *(const bf16x8*)(pbase + (1*4 + ks) * 1024 + lane * 16);
      const bf16x8 vf0 = *(const bf16x8*)(vbuf + (0*4 + ks) * 1024 + lane * 16);
      const bf16x8 vf1 = *(const bf16x8*)(vbuf + (1*4 + ks) * 1024 + lane * 16);
      oacc[0][0] = __builtin_amdgcn_mfma_f32_32x32x16_bf16(pf0, vf0, oacc[0][0], 0, 0, 0);
      oacc[0][1] = __builtin_amdgcn_mfma_f32_32x32x16_bf16(pf0, vf1, oacc[0][1], 0, 0, 0);
      oacc[1][0] = __builtin_amdgcn_mfma_f32_32x32x16_bf16(pf1, vf0, oacc[1][0], 0, 0, 0);
      oacc[1][1] = __builtin_amdgcn_mfma_f32_32x32x16_bf16(pf1, vf1, oacc[1][1], 0, 0, 0);
    }
  }

  // combine the two kc-halves held by lane pairs (l, l^32)
#pragma unroll
  for (int qt2 = 0; qt2 < 2; ++qt2)
    lsum[qt2] += __shfl_xor(lsum[qt2], 32);

  float* Op = s ? Op1 : Op0;
#pragma unroll
  for (int qt2 = 0; qt2 < 2; ++qt2)
#pragma unroll
    for (int dt = 0; dt < 2; ++dt)
#pragma unroll
      for (int r = 0; r < 16; ++r) {
        const int qrow = qw + qt2*32 + (r & 3) + 8*(r >> 2) + 4*h;
        Op[(size_t)bh * 65536 + (size_t)qrow * 64 + dt*32 + l31] = oacc[qt2][dt][r];
      }
  if (h == 0) {
#pragma unroll
    for (int qt2 = 0; qt2 < 2; ++qt2)
      Ls[(size_t)s * 65536 + bh * 1024 + qw + qt2*32 + l31] = lsum[qt2];
  }
}

// combine split-K halves: O = (O0+O1)/(l0+l1), write bf16 Ab [B*LQ, H]
__global__ __launch_bounds__(256) void attn_reduce_kernel(
    const float* __restrict__ Op0, const float* __restrict__ Op1,
    const float* __restrict__ Ls, unsigned short* __restrict__ Ab)
{
  const int g   = blockIdx.x * 256 + threadIdx.x;   // 524288 threads
  const int bhq = g >> 3;
  const int d8  = (g & 7) * 8;
  const float inv = 1.f / (Ls[bhq] + Ls[65536 + bhq]);
  const size_t base = (size_t)bhq * 64 + d8;
  const float4 a0 = *(const float4*)(Op0 + base);
  const float4 a1 = *(const float4*)(Op0 + base + 4);
  const float4 b0 = *(const float4*)(Op1 + base);
  const float4 b1 = *(const float4*)(Op1 + base + 4);
  const int bh = bhq >> 10, qq = bhq & 1023;
  const int bb = bh >> 4, hh = bh & 15;
  unsigned short* dst = Ab + (size_t)(bb * kLQ + qq) * kH + hh * 64 + d8;
  ushort4 o0, o1;
  o0.x = f2bf((a0.x + b0.x) * inv); o0.y = f2bf((a0.y + b0.y) * inv);
  o0.z = f2bf((a0.z + b0.z) * inv); o0.w = f2bf((a0.w + b0.w) * inv);
  o1.x = f2bf((a1.x + b1.x) * inv); o1.y = f2bf((a1.y + b1.y) * inv);
  o1.z = f2bf((a1.z + b1.z) * inv); o1.w = f2bf((a1.w + b1.w) * inv);
  *(ushort4*)dst = o0;
  *(ushort4*)(dst + 4) = o1;
}

extern "C" void kernel_launch(void* const* d_in, const int* in_sizes, int n_in,
                              void* d_out, int out_size, void* d_ws, size_t ws_size,
                              hipStream_t stream) {
  (void)in_sizes; (void)n_in; (void)out_size; (void)ws_size;
  const float* query = (const float*)d_in[0];
  const float* key   = (const float*)d_in[1];
  const float* value = (const float*)d_in[2];
  const float* Wq = (const float*)d_in[3];
  const float* bq = (const float*)d_in[4];
  const float* Wk = (const float*)d_in[5];
  const float* bk = (const float*)d_in[6];
  const float* Wv = (const float*)d_in[7];
  const float* bv = (const float*)d_in[8];
  const float* Wo = (const float*)d_in[9];
  const float* bo = (const float*)d_in[10];
  float* out = (float*)d_out;

  unsigned short* ws  = (unsigned short*)d_ws;
  unsigned short* qA  = ws;                  // 4*1024*768
  unsigned short* kA  = qA  + 3145728;       // 4*2048*512
  unsigned short* vA  = kA  + 4194304;
  unsigned short* WqT = vA  + 4194304;       // 1024*768
  unsigned short* WkT = WqT + 786432;        // 1024*512
  unsigned short* WvT = WkT + 524288;
  unsigned short* WoT = WvT + 524288;        // 1024*1024
  unsigned short* Qb  = WoT + 1048576;       // 4096*1024
  unsigned short* Kb  = Qb  + 4194304;       // 8192*1024
  unsigned short* Vtw = Kb  + 8388608;       // 4096*2048 (transposed V)
  unsigned short* Ab  = Vtw + 8388608;       // 4096*1024

  // split-K partials: Op0 overlays qA/kA (consumed before attn); Ls after Op0
  // (inside vA region, also consumed); Op1 after Ab. Peak ws ~96 MB.
  float* Op0 = (float*)ws;                       // 4,194,304 floats
  float* Lsp = Op0 + 4194304;                    // 131,072 floats
  float* Op1 = (float*)(Ab + 4194304);           // 4,194,304 floats

  dim3 blk(256);
  prep_kernel<<<6336, blk, 0, stream>>>(query, key, value, Wq, Wk, Wv, Wo,
                                        qA, kA, vA, WqT, WkT, WvT, WoT);
  qkv_gemm_kernel<<<640, blk, 0, stream>>>(qA, WqT, bq, Qb,
                                           kA, WkT, bk, Kb,
                                           vA, WvT, bv, Vtw);
  attn_mfma_kernel<<<512, blk, 0, stream>>>(Qb, Kb, Vtw, Op0, Op1, Lsp);
  attn_reduce_kernel<<<2048, blk, 0, stream>>>(Op0, Op1, Lsp, Ab);
  out_gemm_kernel<<<dim3(8, 32), blk, 0, stream>>>(Ab, WoT, bo, out);
}

// Round 9
// 260.952 us; speedup vs baseline: 1.0170x; 1.0170x over previous
//
#include <hip/hip_runtime.h>
#include <math.h>

using bf16x8 = __attribute__((ext_vector_type(8))) short;
using f32x4  = __attribute__((ext_vector_type(4))) float;
using f32x16 = __attribute__((ext_vector_type(16))) float;

namespace {
constexpr int kB  = 4;
constexpr int kLQ = 1024;
constexpr int kLK = 2048;
constexpr int kH  = 1024;
constexpr int kHD = 64;
}

__device__ __forceinline__ unsigned short f2bf(float x) {
  union { float f; unsigned int u; } v; v.f = x;
  unsigned int r = v.u + 0x7fffu + ((v.u >> 16) & 1u);   // RNE
  return (unsigned short)(r >> 16);
}
__device__ __forceinline__ unsigned int bfT(float x) {   // truncation, as u32
  union { float f; unsigned int u; } v; v.f = x;
  return v.u >> 16;
}

// async global->LDS 16B copy
typedef const __attribute__((address_space(1))) unsigned int guint_t;
typedef __attribute__((address_space(3))) unsigned int luint_t;
__device__ __forceinline__ void g2l16(const void* g, void* l) {
  __builtin_amdgcn_global_load_lds(
      (guint_t*)g,
      (luint_t*)(unsigned int)(unsigned long long)l,
      16, 0, 0);
}

// --------- fused prep: fp32->bf16 casts (q,k,v) + 4 weight transposes --------
__global__ __launch_bounds__(256) void prep_kernel(
    const float* __restrict__ q, const float* __restrict__ k,
    const float* __restrict__ v, const float* __restrict__ Wq,
    const float* __restrict__ Wk, const float* __restrict__ Wv,
    const float* __restrict__ Wo, unsigned short* __restrict__ qo,
    unsigned short* __restrict__ ko, unsigned short* __restrict__ vo,
    unsigned short* __restrict__ WqT, unsigned short* __restrict__ WkT,
    unsigned short* __restrict__ WvT, unsigned short* __restrict__ WoT)
{
  __shared__ float tile[64][65];
  const int t = threadIdx.x;
  if (blockIdx.x < 5632) {
    int c = blockIdx.x * 256 + t;
    const float* src; unsigned short* dst;
    if (c < 393216)      { src = q; dst = qo; }
    else if (c < 917504) { src = k; dst = ko; c -= 393216; }
    else                 { src = v; dst = vo; c -= 917504; }
    const int i = c * 8;
    const float4 a = *(const float4*)(src + i);
    const float4 b = *(const float4*)(src + i + 4);
    uint4 o;
    o.x = (unsigned int)f2bf(a.x) | ((unsigned int)f2bf(a.y) << 16);
    o.y = (unsigned int)f2bf(a.z) | ((unsigned int)f2bf(a.w) << 16);
    o.z = (unsigned int)f2bf(b.x) | ((unsigned int)f2bf(b.y) << 16);
    o.w = (unsigned int)f2bf(b.z) | ((unsigned int)f2bf(b.w) << 16);
    *(uint4*)(dst + i) = o;
    return;
  }
  int id = blockIdx.x - 5632;
  const float* W; unsigned short* Wt; int Kd;
  if (id < 192)      { W = Wq; Wt = WqT; Kd = 768; }
  else if (id < 320) { W = Wk; Wt = WkT; Kd = 512;  id -= 192; }
  else if (id < 448) { W = Wv; Wt = WvT; Kd = 512;  id -= 320; }
  else               { W = Wo; Wt = WoT; Kd = 1024; id -= 448; }
  const int Nd = 1024;
  const int n0 = (id & 15) * 64;
  const int k0 = (id >> 4) * 64;
  const int rr = t >> 4;
  const int c4 = t & 15;
#pragma unroll
  for (int i = 0; i < 4; ++i) {
    const int row = i * 16 + rr;
    const float4 vv = *(const float4*)(W + (size_t)(k0 + row) * Nd + n0 + c4 * 4);
    tile[row][c4*4+0] = vv.x; tile[row][c4*4+1] = vv.y;
    tile[row][c4*4+2] = vv.z; tile[row][c4*4+3] = vv.w;
  }
  __syncthreads();
#pragma unroll
  for (int i = 0; i < 4; ++i) {
    const int n = i * 16 + rr;
    ushort4 o;
    o.x = f2bf(tile[c4*4+0][n]); o.y = f2bf(tile[c4*4+1][n]);
    o.z = f2bf(tile[c4*4+2][n]); o.w = f2bf(tile[c4*4+3][n]);
    *(ushort4*)(Wt + (size_t)(n0 + n) * Kd + k0 + c4 * 4) = o;
  }
}

// ---- 128x256 GEMM body (qkv): BK=32, double-buffered g2l, 4 waves -----------
__device__ __forceinline__ void gemm_body256(
    const unsigned short* __restrict__ A, const unsigned short* __restrict__ Bt,
    const float* __restrict__ bias, unsigned short* __restrict__ Cout,
    int N, int K, int bx, int by, int mode, char* lds)
{
  const int t    = threadIdx.x;
  const int lane = t & 63;
  const int w    = t >> 6;
  const int l15  = lane & 15;
  const int lq8  = (lane >> 4) * 8;
  const int lq4  = (lane >> 4) * 4;
  const int r0   = by * 128;
  const int c0   = bx * 256;
  const int wm   = w >> 1, wn = w & 1;

  f32x4 acc[4][8] = {};

#pragma unroll
  for (int i = 0; i < 6; ++i) {
    const int g = w * 6 + i;
    const unsigned short* src = (g < 8) ? A : Bt;
    const int rbase = (g < 8) ? (r0 + g * 16) : (c0 + (g - 8) * 16);
    g2l16(src + (size_t)(rbase + l15) * K + lq8, lds + g * 1024 + lane * 16);
  }

  int pb = 0;
  for (int k0 = 0; k0 < K; k0 += 32, pb ^= 1) {
    __syncthreads();
    char* buf = lds + pb * 24576;
    if (k0 + 32 < K) {
      char* nbuf = lds + (pb ^ 1) * 24576;
#pragma unroll
      for (int i = 0; i < 6; ++i) {
        const int g = w * 6 + i;
        const unsigned short* src = (g < 8) ? A : Bt;
        const int rbase = (g < 8) ? (r0 + g * 16) : (c0 + (g - 8) * 16);
        g2l16(src + (size_t)(rbase + l15) * K + k0 + 32 + lq8, nbuf + g * 1024 + lane * 16);
      }
    }
    bf16x8 af[4], bfr[8];
#pragma unroll
    for (int i = 0; i < 4; ++i) af[i]  = *(const bf16x8*)(buf + (wm*4 + i) * 1024 + lane * 16);
#pragma unroll
    for (int j = 0; j < 8; ++j) bfr[j] = *(const bf16x8*)(buf + 8192 + (wn*8 + j) * 1024 + lane * 16);
#pragma unroll
    for (int i = 0; i < 4; ++i)
#pragma unroll
      for (int j = 0; j < 8; ++j)
        acc[i][j] = __builtin_amdgcn_mfma_f32_16x16x32_bf16(af[i], bfr[j], acc[i][j], 0, 0, 0);
  }

#pragma unroll
  for (int j = 0; j < 8; ++j) {
    const int col = c0 + wn * 128 + j * 16 + l15;
    const float bcol = bias[col];
#pragma unroll
    for (int i = 0; i < 4; ++i) {
      const int row = r0 + wm * 64 + i * 16 + lq4;
      if (mode == 1) {
#pragma unroll
        for (int r = 0; r < 4; ++r) Cout[(size_t)(row + r) * N + col] = f2bf(acc[i][j][r] + bcol);
      } else {
        const int bb = row >> 11;            // kLK = 2048
        const int lk = row & 2047;
        ushort4 o;
        o.x = f2bf(acc[i][j][0] + bcol); o.y = f2bf(acc[i][j][1] + bcol);
        o.z = f2bf(acc[i][j][2] + bcol); o.w = f2bf(acc[i][j][3] + bcol);
        *(ushort4*)(Cout + (size_t)(bb * kH + col) * kLK + lk) = o;
      }
    }
  }
}

// fused Q/K/V projections: blocks 0..127 Q | 128..383 K | 384..639 V
__global__ __launch_bounds__(256) void qkv_gemm_kernel(
    const unsigned short* __restrict__ qA, const unsigned short* __restrict__ WqT,
    const float* __restrict__ bq, unsigned short* __restrict__ Qb,
    const unsigned short* __restrict__ kA, const unsigned short* __restrict__ WkT,
    const float* __restrict__ bk, unsigned short* __restrict__ Kb,
    const unsigned short* __restrict__ vA, const unsigned short* __restrict__ WvT,
    const float* __restrict__ bv, unsigned short* __restrict__ Vtw)
{
  __shared__ __align__(16) char lds[49152];
  int id = blockIdx.x;
  if (id < 128) {
    gemm_body256(qA, WqT, bq, Qb, 1024, 768, id & 3, id >> 2, 1, lds);
  } else if (id < 384) {
    id -= 128;
    gemm_body256(kA, WkT, bk, Kb, 1024, 512, id & 3, id >> 2, 1, lds);
  } else {
    id -= 384;
    gemm_body256(vA, WvT, bv, Vtw, 1024, 512, id & 3, id >> 2, 2, lds);
  }
}

// out projection: 128x128 tile, BK=32, double-buffered, fp32 out, grid (8,32)
__global__ __launch_bounds__(256) void out_gemm_kernel(
    const unsigned short* __restrict__ A, const unsigned short* __restrict__ Bt,
    const float* __restrict__ bias, float* __restrict__ C)
{
  __shared__ __align__(16) char lds[32768];
  const int t    = threadIdx.x;
  const int lane = t & 63;
  const int w    = t >> 6;
  const int l15  = lane & 15;
  const int lq8  = (lane >> 4) * 8;
  const int lq4  = (lane >> 4) * 4;
  const int r0   = blockIdx.y * 128;
  const int c0   = blockIdx.x * 128;
  const int wm   = w >> 1, wn = w & 1;
  const int N = 1024, K = 1024;

  f32x4 acc[4][4] = {};

#pragma unroll
  for (int i = 0; i < 4; ++i) {
    const int g = w * 4 + i;
    const unsigned short* src = (g < 8) ? A : Bt;
    const int rbase = (g < 8) ? (r0 + g * 16) : (c0 + (g - 8) * 16);
    g2l16(src + (size_t)(rbase + l15) * K + lq8, lds + g * 1024 + lane * 16);
  }
  int pb = 0;
  for (int k0 = 0; k0 < K; k0 += 32, pb ^= 1) {
    __syncthreads();
    char* buf = lds + pb * 16384;
    if (k0 + 32 < K) {
      char* nbuf = lds + (pb ^ 1) * 16384;
#pragma unroll
      for (int i = 0; i < 4; ++i) {
        const int g = w * 4 + i;
        const unsigned short* src = (g < 8) ? A : Bt;
        const int rbase = (g < 8) ? (r0 + g * 16) : (c0 + (g - 8) * 16);
        g2l16(src + (size_t)(rbase + l15) * K + k0 + 32 + lq8, nbuf + g * 1024 + lane * 16);
      }
    }
    bf16x8 af[4], bfr[4];
#pragma unroll
    for (int i = 0; i < 4; ++i) af[i]  = *(const bf16x8*)(buf + (wm*4 + i) * 1024 + lane * 16);
#pragma unroll
    for (int j = 0; j < 4; ++j) bfr[j] = *(const bf16x8*)(buf + 8192 + (wn*4 + j) * 1024 + lane * 16);
#pragma unroll
    for (int i = 0; i < 4; ++i)
#pragma unroll
      for (int j = 0; j < 4; ++j)
        acc[i][j] = __builtin_amdgcn_mfma_f32_16x16x32_bf16(af[i], bfr[j], acc[i][j], 0, 0, 0);
  }
#pragma unroll
  for (int j = 0; j < 4; ++j) {
    const int col = c0 + wn * 64 + j * 16 + l15;
    const float bcol = bias[col];
#pragma unroll
    for (int i = 0; i < 4; ++i) {
      const int row = r0 + wm * 64 + i * 16 + lq4;
#pragma unroll
      for (int r = 0; r < 4; ++r) C[(size_t)(row + r) * N + col] = acc[i][j][r] + bcol;
    }
  }
}

// --------------- MFMA flash attention, 32x32 S^T path, no split-K ------------
// Q [B*LQ,H], K [B*LK,H], Vt [B*H,LK] bf16, O=Ab [B*LQ,H] bf16.
// 64 q-rows/block, 2 waves x 32 q; kc loop = 32 iters of 64. Grid 1024 =
// qb*64+bh (XCD locality); LDS 40KB -> 4 blocks/CU (4 barrier groups, 8 waves).
// S^T = K*Q^T (32x32x16): C rows = kc -> packed b64 P-stores matching the PV
// A-frag layout exactly (HW-verified in r8). O = P*V. p=exp2(s*log2e/8).
__global__ __launch_bounds__(128) void attn_mfma_kernel(
    const unsigned short* __restrict__ Q, const unsigned short* __restrict__ K,
    const unsigned short* __restrict__ Vt, unsigned short* __restrict__ O)
{
  // K dbuf [0,16K) | V dbuf [16K,32K) | P [32K + w*4K)
  __shared__ __align__(16) char lds[40960];
  const int t    = threadIdx.x;
  const int lane = t & 63;
  const int w    = t >> 6;        // 0..1
  const int l31  = lane & 31;
  const int h    = lane >> 5;
  const int flat = blockIdx.x;
  const int bh   = flat & 63;
  const int qb   = flat >> 6;     // 0..15
  const int hh   = bh & 15;
  const int b    = bh >> 4;
  const int q0   = qb * 64;
  const int hoff = hh * kHD;
  const int qw   = q0 + w * 32;

  // Q B-frags: n = q = l31, k = d = h*8+j
  bf16x8 qf[4];
#pragma unroll
  for (int ds_ = 0; ds_ < 4; ++ds_)
    qf[ds_] = *(const bf16x8*)(Q + (size_t)(b*kLQ + qw + l31) * kH + hoff + ds_*16 + h*8);

  f32x16 oacc[2] = {};
  float lsum = 0.f;
  char* const pw = lds + 32768 + w * 4096;

  // prologue: wave0 prefetches K tile 0 (chunks 0..7), wave1 V tile 0
#pragma unroll
  for (int i = 0; i < 8; ++i) {
    const int g = w * 8 + i;
    if (g < 8) {
      g2l16(K + (size_t)(b*kLK + (g >> 2)*32 + l31) * kH + hoff + (g & 3)*16 + h*8,
            lds + g * 1024 + lane * 16);
    } else {
      const int gg = g - 8;
      g2l16(Vt + (size_t)(b*kH + hoff + (gg >> 2)*32 + l31) * kLK + (gg & 3)*16 + h*8,
            lds + 16384 + gg * 1024 + lane * 16);
    }
  }

  for (int kt = 0; kt < 32; ++kt) {
    __syncthreads();   // drains tile-kt prefetch (issued one full iter ago)
    char* kbuf = lds + (kt & 1) * 8192;
    char* vbuf = lds + 16384 + (kt & 1) * 8192;
    if (kt + 1 < 32) {
      const int kc1 = (kt + 1) * 64;
      char* nk = lds + ((kt + 1) & 1) * 8192;
      char* nv = lds + 16384 + ((kt + 1) & 1) * 8192;
#pragma unroll
      for (int i = 0; i < 8; ++i) {
        const int g = w * 8 + i;
        if (g < 8) {
          g2l16(K + (size_t)(b*kLK + kc1 + (g >> 2)*32 + l31) * kH + hoff + (g & 3)*16 + h*8,
                nk + g * 1024 + lane * 16);
        } else {
          const int gg = g - 8;
          g2l16(Vt + (size_t)(b*kH + hoff + (gg >> 2)*32 + l31) * kLK + kc1 + (gg & 3)*16 + h*8,
                nv + gg * 1024 + lane * 16);
        }
      }
    }

    // S^T = K * Q^T : 2 kc-tiles (32 kc each) x contraction d=64 in 4 steps
    f32x16 sacc[2] = {};
#pragma unroll
    for (int ds_ = 0; ds_ < 4; ++ds_) {
      const bf16x8 kf0 = *(const bf16x8*)(kbuf + (0*4 + ds_) * 1024 + lane * 16);
      const bf16x8 kf1 = *(const bf16x8*)(kbuf + (1*4 + ds_) * 1024 + lane * 16);
      sacc[0] = __builtin_amdgcn_mfma_f32_32x32x16_bf16(kf0, qf[ds_], sacc[0], 0, 0, 0);
      sacc[1] = __builtin_amdgcn_mfma_f32_32x32x16_bf16(kf1, qf[ds_], sacc[1], 0, 0, 0);
    }

    // exp + packed b64 P-store; store off = kct*2048 + g4*512 + l31*16 + h*8
#pragma unroll
    for (int kct = 0; kct < 2; ++kct)
#pragma unroll
      for (int g4 = 0; g4 < 4; ++g4) {
        const float e0 = __builtin_amdgcn_exp2f(sacc[kct][g4*4+0] * 0.18033688011112042f);
        const float e1 = __builtin_amdgcn_exp2f(sacc[kct][g4*4+1] * 0.18033688011112042f);
        const float e2 = __builtin_amdgcn_exp2f(sacc[kct][g4*4+2] * 0.18033688011112042f);
        const float e3 = __builtin_amdgcn_exp2f(sacc[kct][g4*4+3] * 0.18033688011112042f);
        lsum += (e0 + e1) + (e2 + e3);
        uint2 u;
        u.x = bfT(e0) | (bfT(e1) << 16);
        u.y = bfT(e2) | (bfT(e3) << 16);
        *(uint2*)(pw + kct*2048 + g4*512 + l31*16 + h*8) = u;
      }

    // O += P * V : A=P (m=q), B=V (n=d); contraction kc=64 in 4 steps
#pragma unroll
    for (int ks = 0; ks < 4; ++ks) {
      const bf16x8 pf  = *(const bf16x8*)(pw + ks * 1024 + lane * 16);
      const bf16x8 vf0 = *(const bf16x8*)(vbuf + (0*4 + ks) * 1024 + lane * 16);
      const bf16x8 vf1 = *(const bf16x8*)(vbuf + (1*4 + ks) * 1024 + lane * 16);
      oacc[0] = __builtin_amdgcn_mfma_f32_32x32x16_bf16(pf, vf0, oacc[0], 0, 0, 0);
      oacc[1] = __builtin_amdgcn_mfma_f32_32x32x16_bf16(pf, vf1, oacc[1], 0, 0, 0);
    }
  }

  // lsum held per (q=l31, h-half of kc); combine halves, broadcast 1/l via LDS
  lsum += __shfl_xor(lsum, 32);
  __syncthreads();
  if (h == 0) *(float*)(pw + l31 * 4) = 1.f / lsum;
  __syncthreads();

#pragma unroll
  for (int dt = 0; dt < 2; ++dt)
#pragma unroll
    for (int r = 0; r < 16; ++r) {
      const int ql = (r & 3) + 8 * (r >> 2) + 4 * h;   // 0..31
      const float inv = *(const float*)(pw + ql * 4);
      O[(size_t)(b*kLQ + qw + ql) * kH + hoff + dt*32 + l31] = f2bf(oacc[dt][r] * inv);
    }
}

extern "C" void kernel_launch(void* const* d_in, const int* in_sizes, int n_in,
                              void* d_out, int out_size, void* d_ws, size_t ws_size,
                              hipStream_t stream) {
  (void)in_sizes; (void)n_in; (void)out_size; (void)ws_size;
  const float* query = (const float*)d_in[0];
  const float* key   = (const float*)d_in[1];
  const float* value = (const float*)d_in[2];
  const float* Wq = (const float*)d_in[3];
  const float* bq = (const float*)d_in[4];
  const float* Wk = (const float*)d_in[5];
  const float* bk = (const float*)d_in[6];
  const float* Wv = (const float*)d_in[7];
  const float* bv = (const float*)d_in[8];
  const float* Wo = (const float*)d_in[9];
  const float* bo = (const float*)d_in[10];
  float* out = (float*)d_out;

  unsigned short* ws  = (unsigned short*)d_ws;
  unsigned short* qA  = ws;                  // 4*1024*768
  unsigned short* kA  = qA  + 3145728;       // 4*2048*512
  unsigned short* vA  = kA  + 4194304;
  unsigned short* WqT = vA  + 4194304;       // 1024*768
  unsigned short* WkT = WqT + 786432;        // 1024*512
  unsigned short* WvT = WkT + 524288;
  unsigned short* WoT = WvT + 524288;        // 1024*1024
  unsigned short* Qb  = WoT + 1048576;       // 4096*1024
  unsigned short* Kb  = Qb  + 4194304;       // 8192*1024
  unsigned short* Vtw = Kb  + 8388608;       // 4096*2048 (transposed V)
  unsigned short* Ab  = Vtw + 8388608;       // 4096*1024

  dim3 blk(256);
  prep_kernel<<<6336, blk, 0, stream>>>(query, key, value, Wq, Wk, Wv, Wo,
                                        qA, kA, vA, WqT, WkT, WvT, WoT);
  qkv_gemm_kernel<<<640, blk, 0, stream>>>(qA, WqT, bq, Qb,
                                           kA, WkT, bk, Kb,
                                           vA, WvT, bv, Vtw);
  attn_mfma_kernel<<<1024, dim3(128), 0, stream>>>(Qb, Kb, Vtw, Ab);
  out_gemm_kernel<<<dim3(8, 32), blk, 0, stream>>>(Ab, WoT, bo, out);
}

// Round 10
// 257.914 us; speedup vs baseline: 1.0289x; 1.0118x over previous
//
#include <hip/hip_runtime.h>
#include <math.h>

using bf16x8 = __attribute__((ext_vector_type(8))) short;
using f32x4  = __attribute__((ext_vector_type(4))) float;

namespace {
constexpr int kB  = 4;
constexpr int kLQ = 1024;
constexpr int kLK = 2048;
constexpr int kH  = 1024;
constexpr int kHD = 64;
}

__device__ __forceinline__ unsigned short f2bf(float x) {
  union { float f; unsigned int u; } v; v.f = x;
  unsigned int r = v.u + 0x7fffu + ((v.u >> 16) & 1u);   // RNE
  return (unsigned short)(r >> 16);
}

// async global->LDS 16B copy
typedef const __attribute__((address_space(1))) unsigned int guint_t;
typedef __attribute__((address_space(3))) unsigned int luint_t;
__device__ __forceinline__ void g2l16(const void* g, void* l) {
  __builtin_amdgcn_global_load_lds(
      (guint_t*)g,
      (luint_t*)(unsigned int)(unsigned long long)l,
      16, 0, 0);
}

// --------- fused prep: fp32->bf16 casts (q,k,v) + 4 weight transposes --------
__global__ __launch_bounds__(256) void prep_kernel(
    const float* __restrict__ q, const float* __restrict__ k,
    const float* __restrict__ v, const float* __restrict__ Wq,
    const float* __restrict__ Wk, const float* __restrict__ Wv,
    const float* __restrict__ Wo, unsigned short* __restrict__ qo,
    unsigned short* __restrict__ ko, unsigned short* __restrict__ vo,
    unsigned short* __restrict__ WqT, unsigned short* __restrict__ WkT,
    unsigned short* __restrict__ WvT, unsigned short* __restrict__ WoT)
{
  __shared__ float tile[64][65];
  const int t = threadIdx.x;
  if (blockIdx.x < 5632) {
    int c = blockIdx.x * 256 + t;
    const float* src; unsigned short* dst;
    if (c < 393216)      { src = q; dst = qo; }
    else if (c < 917504) { src = k; dst = ko; c -= 393216; }
    else                 { src = v; dst = vo; c -= 917504; }
    const int i = c * 8;
    const float4 a = *(const float4*)(src + i);
    const float4 b = *(const float4*)(src + i + 4);
    uint4 o;
    o.x = (unsigned int)f2bf(a.x) | ((unsigned int)f2bf(a.y) << 16);
    o.y = (unsigned int)f2bf(a.z) | ((unsigned int)f2bf(a.w) << 16);
    o.z = (unsigned int)f2bf(b.x) | ((unsigned int)f2bf(b.y) << 16);
    o.w = (unsigned int)f2bf(b.z) | ((unsigned int)f2bf(b.w) << 16);
    *(uint4*)(dst + i) = o;
    return;
  }
  int id = blockIdx.x - 5632;
  const float* W; unsigned short* Wt; int Kd;
  if (id < 192)      { W = Wq; Wt = WqT; Kd = 768; }
  else if (id < 320) { W = Wk; Wt = WkT; Kd = 512;  id -= 192; }
  else if (id < 448) { W = Wv; Wt = WvT; Kd = 512;  id -= 320; }
  else               { W = Wo; Wt = WoT; Kd = 1024; id -= 448; }
  const int Nd = 1024;
  const int n0 = (id & 15) * 64;
  const int k0 = (id >> 4) * 64;
  const int rr = t >> 4;
  const int c4 = t & 15;
#pragma unroll
  for (int i = 0; i < 4; ++i) {
    const int row = i * 16 + rr;
    const float4 vv = *(const float4*)(W + (size_t)(k0 + row) * Nd + n0 + c4 * 4);
    tile[row][c4*4+0] = vv.x; tile[row][c4*4+1] = vv.y;
    tile[row][c4*4+2] = vv.z; tile[row][c4*4+3] = vv.w;
  }
  __syncthreads();
#pragma unroll
  for (int i = 0; i < 4; ++i) {
    const int n = i * 16 + rr;
    ushort4 o;
    o.x = f2bf(tile[c4*4+0][n]); o.y = f2bf(tile[c4*4+1][n]);
    o.z = f2bf(tile[c4*4+2][n]); o.w = f2bf(tile[c4*4+3][n]);
    *(ushort4*)(Wt + (size_t)(n0 + n) * Kd + k0 + c4 * 4) = o;
  }
}

// ---- 128x256 GEMM body (qkv): BK=32, double-buffered g2l, 4 waves -----------
__device__ __forceinline__ void gemm_body256(
    const unsigned short* __restrict__ A, const unsigned short* __restrict__ Bt,
    const float* __restrict__ bias, unsigned short* __restrict__ Cout,
    int N, int K, int bx, int by, int mode, char* lds)
{
  const int t    = threadIdx.x;
  const int lane = t & 63;
  const int w    = t >> 6;
  const int l15  = lane & 15;
  const int lq8  = (lane >> 4) * 8;
  const int lq4  = (lane >> 4) * 4;
  const int r0   = by * 128;
  const int c0   = bx * 256;
  const int wm   = w >> 1, wn = w & 1;

  f32x4 acc[4][8] = {};

#pragma unroll
  for (int i = 0; i < 6; ++i) {
    const int g = w * 6 + i;
    const unsigned short* src = (g < 8) ? A : Bt;
    const int rbase = (g < 8) ? (r0 + g * 16) : (c0 + (g - 8) * 16);
    g2l16(src + (size_t)(rbase + l15) * K + lq8, lds + g * 1024 + lane * 16);
  }

  int pb = 0;
  for (int k0 = 0; k0 < K; k0 += 32, pb ^= 1) {
    __syncthreads();
    char* buf = lds + pb * 24576;
    if (k0 + 32 < K) {
      char* nbuf = lds + (pb ^ 1) * 24576;
#pragma unroll
      for (int i = 0; i < 6; ++i) {
        const int g = w * 6 + i;
        const unsigned short* src = (g < 8) ? A : Bt;
        const int rbase = (g < 8) ? (r0 + g * 16) : (c0 + (g - 8) * 16);
        g2l16(src + (size_t)(rbase + l15) * K + k0 + 32 + lq8, nbuf + g * 1024 + lane * 16);
      }
    }
    bf16x8 af[4], bfr[8];
#pragma unroll
    for (int i = 0; i < 4; ++i) af[i]  = *(const bf16x8*)(buf + (wm*4 + i) * 1024 + lane * 16);
#pragma unroll
    for (int j = 0; j < 8; ++j) bfr[j] = *(const bf16x8*)(buf + 8192 + (wn*8 + j) * 1024 + lane * 16);
#pragma unroll
    for (int i = 0; i < 4; ++i)
#pragma unroll
      for (int j = 0; j < 8; ++j)
        acc[i][j] = __builtin_amdgcn_mfma_f32_16x16x32_bf16(af[i], bfr[j], acc[i][j], 0, 0, 0);
  }

#pragma unroll
  for (int j = 0; j < 8; ++j) {
    const int col = c0 + wn * 128 + j * 16 + l15;
    const float bcol = bias[col];
#pragma unroll
    for (int i = 0; i < 4; ++i) {
      const int row = r0 + wm * 64 + i * 16 + lq4;
      if (mode == 1) {
#pragma unroll
        for (int r = 0; r < 4; ++r) Cout[(size_t)(row + r) * N + col] = f2bf(acc[i][j][r] + bcol);
      } else {
        const int bb = row >> 11;            // kLK = 2048
        const int lk = row & 2047;
        ushort4 o;
        o.x = f2bf(acc[i][j][0] + bcol); o.y = f2bf(acc[i][j][1] + bcol);
        o.z = f2bf(acc[i][j][2] + bcol); o.w = f2bf(acc[i][j][3] + bcol);
        *(ushort4*)(Cout + (size_t)(bb * kH + col) * kLK + lk) = o;
      }
    }
  }
}

// fused Q/K/V projections: blocks 0..127 Q | 128..383 K | 384..639 V
__global__ __launch_bounds__(256) void qkv_gemm_kernel(
    const unsigned short* __restrict__ qA, const unsigned short* __restrict__ WqT,
    const float* __restrict__ bq, unsigned short* __restrict__ Qb,
    const unsigned short* __restrict__ kA, const unsigned short* __restrict__ WkT,
    const float* __restrict__ bk, unsigned short* __restrict__ Kb,
    const unsigned short* __restrict__ vA, const unsigned short* __restrict__ WvT,
    const float* __restrict__ bv, unsigned short* __restrict__ Vtw)
{
  __shared__ __align__(16) char lds[49152];
  int id = blockIdx.x;
  if (id < 128) {
    gemm_body256(qA, WqT, bq, Qb, 1024, 768, id & 3, id >> 2, 1, lds);
  } else if (id < 384) {
    id -= 128;
    gemm_body256(kA, WkT, bk, Kb, 1024, 512, id & 3, id >> 2, 1, lds);
  } else {
    id -= 384;
    gemm_body256(vA, WvT, bv, Vtw, 1024, 512, id & 3, id >> 2, 2, lds);
  }
}

// out projection: 128x128 tile, BK=32, double-buffered, fp32 out, grid (8,32)
__global__ __launch_bounds__(256) void out_gemm_kernel(
    const unsigned short* __restrict__ A, const unsigned short* __restrict__ Bt,
    const float* __restrict__ bias, float* __restrict__ C)
{
  __shared__ __align__(16) char lds[32768];
  const int t    = threadIdx.x;
  const int lane = t & 63;
  const int w    = t >> 6;
  const int l15  = lane & 15;
  const int lq8  = (lane >> 4) * 8;
  const int lq4  = (lane >> 4) * 4;
  const int r0   = blockIdx.y * 128;
  const int c0   = blockIdx.x * 128;
  const int wm   = w >> 1, wn = w & 1;
  const int N = 1024, K = 1024;

  f32x4 acc[4][4] = {};

#pragma unroll
  for (int i = 0; i < 4; ++i) {
    const int g = w * 4 + i;
    const unsigned short* src = (g < 8) ? A : Bt;
    const int rbase = (g < 8) ? (r0 + g * 16) : (c0 + (g - 8) * 16);
    g2l16(src + (size_t)(rbase + l15) * K + lq8, lds + g * 1024 + lane * 16);
  }
  int pb = 0;
  for (int k0 = 0; k0 < K; k0 += 32, pb ^= 1) {
    __syncthreads();
    char* buf = lds + pb * 16384;
    if (k0 + 32 < K) {
      char* nbuf = lds + (pb ^ 1) * 16384;
#pragma unroll
      for (int i = 0; i < 4; ++i) {
        const int g = w * 4 + i;
        const unsigned short* src = (g < 8) ? A : Bt;
        const int rbase = (g < 8) ? (r0 + g * 16) : (c0 + (g - 8) * 16);
        g2l16(src + (size_t)(rbase + l15) * K + k0 + 32 + lq8, nbuf + g * 1024 + lane * 16);
      }
    }
    bf16x8 af[4], bfr[4];
#pragma unroll
    for (int i = 0; i < 4; ++i) af[i]  = *(const bf16x8*)(buf + (wm*4 + i) * 1024 + lane * 16);
#pragma unroll
    for (int j = 0; j < 4; ++j) bfr[j] = *(const bf16x8*)(buf + 8192 + (wn*4 + j) * 1024 + lane * 16);
#pragma unroll
    for (int i = 0; i < 4; ++i)
#pragma unroll
      for (int j = 0; j < 4; ++j)
        acc[i][j] = __builtin_amdgcn_mfma_f32_16x16x32_bf16(af[i], bfr[j], acc[i][j], 0, 0, 0);
  }
#pragma unroll
  for (int j = 0; j < 4; ++j) {
    const int col = c0 + wn * 64 + j * 16 + l15;
    const float bcol = bias[col];
#pragma unroll
    for (int i = 0; i < 4; ++i) {
      const int row = r0 + wm * 64 + i * 16 + lq4;
#pragma unroll
      for (int r = 0; r < 4; ++r) C[(size_t)(row + r) * N + col] = acc[i][j][r] + bcol;
    }
  }
}

// --------------------- MFMA flash attention (bf16, fp32 acc) -----------------
// r6 pipeline structure, occupancy-tuned: 64 q-rows/block, 4 waves x 16 q-rows,
// kc-tile 64. LDS 33 KB -> 4 blocks/CU x 4 waves = 16 waves/CU (4/SIMD) to hide
// the ~2000-cyc barrier/drain stall measured in r6/r9. V single-buffered (safe:
// barrier A at iter top guarantees all PV reads of V_{t-1} are done before the
// V_t g2l issues; barrier B drains it). Grid 1024 flat = qb*64+bh (XCD local).
__global__ __launch_bounds__(256, 4) void attn_mfma_kernel(
    const unsigned short* __restrict__ Q, const unsigned short* __restrict__ K,
    const unsigned short* __restrict__ Vt, unsigned short* __restrict__ O)
{
  // K dbuf 2x8K @0 | V 8K @16384 | P 64 rows x 72 bf16 @24576
  __shared__ __align__(16) char lds[33792];
  constexpr int VOFF = 16384;
  constexpr int POFF = 24576;
  const int t    = threadIdx.x;
  const int lane = t & 63;
  const int w    = t >> 6;
  const int l15  = lane & 15;
  const int lq8  = (lane >> 4) * 8;
  const int lq4  = (lane >> 4) * 4;
  const int flat = blockIdx.x;
  const int bh   = flat & 63;
  const int qb   = flat >> 6;     // 0..15
  const int h    = bh & 15;
  const int b    = bh >> 4;
  const int q0   = qb * 64;
  const int hoff = h * kHD;
  const int qw   = w * 16;        // wave's q-row base within block

  bf16x8 qf[2];
#pragma unroll
  for (int kh = 0; kh < 2; ++kh)
    qf[kh] = *(const bf16x8*)(Q + (size_t)(b*kLQ + q0 + qw + l15) * kH + hoff + kh*32 + lq8);

  f32x4 acc[4] = {};
  float lsum[4] = {0.f, 0.f, 0.f, 0.f};

  // prologue: prefetch K_0 into Kbuf[0] (8 chunks, 2 per wave)
#pragma unroll
  for (int i = 0; i < 2; ++i) {
    const int g = w * 2 + i;
    g2l16(K + (size_t)(b*kLK + (g >> 1)*16 + l15) * kH + hoff + (g & 1)*32 + lq8,
          lds + g * 1024 + lane * 16);
  }

  for (int kt = 0; kt < kLK / 64; ++kt) {
    const int kc0 = kt * 64;
    char* kbuf = lds + (kt & 1) * 8192;
    __syncthreads();   // (A) PV_{t-1} done with V & P; K_t drained by B_{t-1}

    // issue V_t (chunks 0..7) and K_{t+1} (chunks 8..15), 4 per wave
#pragma unroll
    for (int i = 0; i < 4; ++i) {
      const int g = w * 4 + i;
      if (g < 8) {   // V chunk: B-frag order (vd tile, kc half)
        g2l16(Vt + (size_t)(b*kH + hoff + (g >> 1)*16 + l15) * kLK + kc0 + (g & 1)*32 + lq8,
              lds + VOFF + g * 1024 + lane * 16);
      } else if (kt + 1 < kLK / 64) {
        const int gg = g - 8;
        char* nkbuf = lds + ((kt + 1) & 1) * 8192;
        g2l16(K + (size_t)(b*kLK + kc0 + 64 + (gg >> 1)*16 + l15) * kH + hoff + (gg & 1)*32 + lq8,
              nkbuf + gg * 1024 + lane * 16);
      }
    }

    // S = Q K^T : 16 q-rows x 64 kc per wave (8 MFMA)
    f32x4 s[4];
#pragma unroll
    for (int kcf = 0; kcf < 4; ++kcf) {
      const bf16x8 kf0 = *(const bf16x8*)(kbuf + (kcf*2 + 0) * 1024 + lane * 16);
      const bf16x8 kf1 = *(const bf16x8*)(kbuf + (kcf*2 + 1) * 1024 + lane * 16);
      f32x4 z = {};
      z = __builtin_amdgcn_mfma_f32_16x16x32_bf16(qf[0], kf0, z, 0, 0, 0);
      z = __builtin_amdgcn_mfma_f32_16x16x32_bf16(qf[1], kf1, z, 0, 0, 0);
      s[kcf] = z;
    }

    // P = exp2(s*log2e/8); bf16 truncation store (bias cancels via norm)
#pragma unroll
    for (int kcf = 0; kcf < 4; ++kcf)
#pragma unroll
      for (int r = 0; r < 4; ++r) {
        const float p = __builtin_amdgcn_exp2f(s[kcf][r] * 0.18033688011112042f);
        lsum[r] += p;
        union { float f; unsigned int u; } pu; pu.f = p;
        *(unsigned short*)(lds + POFF + ((qw + lq4 + r) * 72 + kcf*16 + l15) * 2) =
            (unsigned short)(pu.u >> 16);
      }

    __syncthreads();   // (B) drains V_t (and K_{t+1}); P rows are wave-private

    // O += P V : 8 MFMA
    bf16x8 pf[2];
#pragma unroll
    for (int kq = 0; kq < 2; ++kq)
      pf[kq] = *(const bf16x8*)(lds + POFF + ((qw + l15) * 72 + kq*32 + lq8) * 2);
#pragma unroll
    for (int vd = 0; vd < 4; ++vd) {
      const bf16x8 vf0 = *(const bf16x8*)(lds + VOFF + (vd*2 + 0) * 1024 + lane * 16);
      const bf16x8 vf1 = *(const bf16x8*)(lds + VOFF + (vd*2 + 1) * 1024 + lane * 16);
      acc[vd] = __builtin_amdgcn_mfma_f32_16x16x32_bf16(pf[0], vf0, acc[vd], 0, 0, 0);
      acc[vd] = __builtin_amdgcn_mfma_f32_16x16x32_bf16(pf[1], vf1, acc[vd], 0, 0, 0);
    }
  }

  // reduce row sums across the 16 lanes sharing each row quad
#pragma unroll
  for (int r = 0; r < 4; ++r) {
    float v = lsum[r];
    v += __shfl_xor(v, 1);
    v += __shfl_xor(v, 2);
    v += __shfl_xor(v, 4);
    v += __shfl_xor(v, 8);
    lsum[r] = 1.f / v;
  }
#pragma unroll
  for (int vd = 0; vd < 4; ++vd)
#pragma unroll
    for (int r = 0; r < 4; ++r)
      O[(size_t)(b*kLQ + q0 + qw + lq4 + r) * kH + hoff + vd*16 + l15] =
          f2bf(acc[vd][r] * lsum[r]);
}

extern "C" void kernel_launch(void* const* d_in, const int* in_sizes, int n_in,
                              void* d_out, int out_size, void* d_ws, size_t ws_size,
                              hipStream_t stream) {
  (void)in_sizes; (void)n_in; (void)out_size; (void)ws_size;
  const float* query = (const float*)d_in[0];
  const float* key   = (const float*)d_in[1];
  const float* value = (const float*)d_in[2];
  const float* Wq = (const float*)d_in[3];
  const float* bq = (const float*)d_in[4];
  const float* Wk = (const float*)d_in[5];
  const float* bk = (const float*)d_in[6];
  const float* Wv = (const float*)d_in[7];
  const float* bv = (const float*)d_in[8];
  const float* Wo = (const float*)d_in[9];
  const float* bo = (const float*)d_in[10];
  float* out = (float*)d_out;

  unsigned short* ws  = (unsigned short*)d_ws;
  unsigned short* qA  = ws;                  // 4*1024*768
  unsigned short* kA  = qA  + 3145728;       // 4*2048*512
  unsigned short* vA  = kA  + 4194304;
  unsigned short* WqT = vA  + 4194304;       // 1024*768
  unsigned short* WkT = WqT + 786432;        // 1024*512
  unsigned short* WvT = WkT + 524288;
  unsigned short* WoT = WvT + 524288;        // 1024*1024
  unsigned short* Qb  = WoT + 1048576;       // 4096*1024
  unsigned short* Kb  = Qb  + 4194304;       // 8192*1024
  unsigned short* Vtw = Kb  + 8388608;       // 4096*2048 (transposed V)
  unsigned short* Ab  = Vtw + 8388608;       // 4096*1024

  dim3 blk(256);
  prep_kernel<<<6336, blk, 0, stream>>>(query, key, value, Wq, Wk, Wv, Wo,
                                        qA, kA, vA, WqT, WkT, WvT, WoT);
  qkv_gemm_kernel<<<640, blk, 0, stream>>>(qA, WqT, bq, Qb,
                                           kA, WkT, bk, Kb,
                                           vA, WvT, bv, Vtw);
  attn_mfma_kernel<<<1024, blk, 0, stream>>>(Qb, Kb, Vtw, Ab);
  out_gemm_kernel<<<dim3(8, 32), blk, 0, stream>>>(Ab, WoT, bo, out);
}